// Round 6
// baseline (930.021 us; speedup 1.0000x reference)
//
#include <hip/hip_runtime.h>
#include <math.h>
#include <stdint.h>

#define TSTEPS 200
#define BATCH  256
#define XDIM   24
#define ADIM   8
#define INDIM  32
#define HID    512
#define OUTD   64

#define NBT 16     // batch teams
#define NUT 16     // unit-tile blocks per team
#define BT  16     // batch rows per block
#define UT  32     // hidden units per block
#define KTOT 544
#define KK_N 17    // K chunks of 32

// ---- workspace byte layout ----
#define XA_OFF   0
#define XA_BYTES (TSTEPS*BATCH*INDIM*2)              // 3,276,800 bf16 [x*mask|a]
#define HB_BYTES (BATCH*HID*2)                       // 262,144 bf16 h
#define HB_OFF(i) (XA_OFF + XA_BYTES + (size_t)(i)*HB_BYTES)   // ring of 3
#define HF_OFF   (XA_OFF + XA_BYTES + 3*(size_t)HB_BYTES)      // final h fp32

// ---- LDS byte layout ----
#define ROWB 1104                     // 64 B xa + 1024 B h + 16 B pad
#define IN_BYTES  (BT*ROWB)           // 17,664 ; double-buffered
#define SCR_OFF   (2*IN_BYTES)        // 35,328 ; per-wave 1 KB scratch
#define SCR_BYTES (8*1024)
// pad to >80 KB so at most 1 block/CU -> 256 blocks spread over 256 CUs
#define LDS_TOTAL 83968

typedef __attribute__((ext_vector_type(8))) short bf16x8;
typedef __attribute__((ext_vector_type(4))) float f32x4;

__device__ __forceinline__ unsigned short f2bf(float f) {
    union { float f; unsigned u; } c; c.f = f;
    unsigned u = c.u;
    return (unsigned short)((u + 0x7fffu + ((u >> 16) & 1u)) >> 16);
}
__device__ __forceinline__ bf16x8 pack8(const float* p) {
    float4 lo = *(const float4*)p, hi = *(const float4*)(p + 4);
    union { unsigned short s[8]; bf16x8 v; } u;
    u.s[0] = f2bf(lo.x); u.s[1] = f2bf(lo.y); u.s[2] = f2bf(lo.z); u.s[3] = f2bf(lo.w);
    u.s[4] = f2bf(hi.x); u.s[5] = f2bf(hi.y); u.s[6] = f2bf(hi.z); u.s[7] = f2bf(hi.w);
    return u.v;
}
__device__ __forceinline__ unsigned long long llc_load64(const unsigned long long* p) {
    return __hip_atomic_load(p, __ATOMIC_RELAXED, __HIP_MEMORY_SCOPE_AGENT);
}
__device__ __forceinline__ void llc_store64(unsigned long long* p, unsigned long long v) {
    __hip_atomic_store(p, v, __ATOMIC_RELAXED, __HIP_MEMORY_SCOPE_AGENT);
}

// ---------------------------------------------------------------------------
// precompute: xa bf16; hbuf0 = 0 (h at s=0), hbuf1/2 = sentinel
__global__ __launch_bounds__(256) void precompute_kernel(
    const float* __restrict__ x, const float* __restrict__ a,
    const float* __restrict__ mask, uint8_t* __restrict__ ws)
{
    unsigned short* xa = (unsigned short*)(ws + XA_OFF);
    const int n = TSTEPS * BATCH * INDIM;
    for (int e = blockIdx.x * 256 + threadIdx.x; e < n; e += gridDim.x * 256) {
        int t = e / (BATCH * INDIM);
        int r = e - t * (BATCH * INDIM);
        int b = r >> 5, j = r & 31;
        float v;
        if (j < XDIM) v = x[(t * BATCH + b) * XDIM + j] * mask[(t * BATCH + b) * XDIM + j];
        else          v = a[(t * BATCH + b) * ADIM + (j - XDIM)];
        xa[e] = f2bf(v);
    }
    unsigned* h0 = (unsigned*)(ws + HB_OFF(0));
    unsigned* h1 = (unsigned*)(ws + HB_OFF(1));
    unsigned* h2 = (unsigned*)(ws + HB_OFF(2));
    const int hn = HB_BYTES / 4;
    for (int e = blockIdx.x * 256 + threadIdx.x; e < hn; e += gridDim.x * 256) {
        h0[e] = 0u; h1[e] = 0xFFFFFFFFu; h2[e] = 0xFFFFFFFFu;
    }
}

// ---------------------------------------------------------------------------
// persistent LSTM: 256 blocks = 16 teams x 16 unit-blocks, 512 thr (8 waves).
// Each block: 16 batch rows x 32 units. Weights in VGPRs; in-wave gate
// transpose; ONE barrier/step; data-sentinel 3-ring over LLC (sc1).
__global__ __launch_bounds__(512, 1) void lstm_persist_kernel(
    const float* __restrict__ W_ih, const float* __restrict__ W_hh,
    const float* __restrict__ b_ih, const float* __restrict__ b_hh,
    uint8_t* __restrict__ ws)
{
    __shared__ __align__(16) uint8_t smem[LDS_TOTAL];
    const int tid = threadIdx.x;
    const int bid = blockIdx.x;
    const int bt = bid >> 4;           // team 0..15
    const int ut = bid & 15;           // unit tile 0..15
    const int b0 = bt * BT;
    const int ug0 = ut * UT;

    const unsigned* xa32 = (const unsigned*)(ws + XA_OFF);
    unsigned long long* hb[3] = {
        (unsigned long long*)(ws + HB_OFF(0)),
        (unsigned long long*)(ws + HB_OFF(1)),
        (unsigned long long*)(ws + HB_OFF(2)) };
    float* hfinal = (float*)(ws + HF_OFF);

    const int w  = tid >> 6, l = tid & 63;
    const int c  = l & 15;             // MFMA col: gate gp = c>>2, unit-sub c&3
    const int kq = l >> 4;             // k-quad
    // wave w owns units ug0 + w*4 .. +3 (all 4 gates)
    const int grow = (c >> 2) * HID + ug0 + w * 4 + (c & 3);

    // ---- B fragments -> registers (constant all 200 steps) ----
    bf16x8 wb[KK_N];
    wb[0] = pack8(W_ih + (size_t)grow * INDIM + kq * 8);
#pragma unroll
    for (int kk = 1; kk < KK_N; ++kk)
        wb[kk] = pack8(W_hh + (size_t)grow * HID + (kk - 1) * 32 + kq * 8);
    const float bias = b_ih[grow] + b_hh[grow];

    // pointwise ownership: lane -> (unit-sub du, row rs)
    const int du = l & 3, rs = l >> 2;
    // staging ownership: thread -> (row prow, slot q)
    const int prow = tid >> 5, q = tid & 31;
    float c_reg = 0.0f;

    float* scr = (float*)(smem + SCR_OFF + w * 1024);

    unsigned xa_next = 0;
    if (q < 16)
        xa_next = xa32[((size_t)(TSTEPS - 1) * BATCH + b0 + prow) * 16 + q];

    for (int s = 0; s < TSTEPS; ++s) {
        uint8_t* inb = smem + (s & 1) * IN_BYTES;

        // xa -> LDS (16 u32 per row)
        if (q < 16)
            *(unsigned*)(inb + prow * ROWB + q * 4) = xa_next;

        // poll + stage h(s): thread owns 4 u64 slots of row (b0+prow)
        {
            const unsigned long long* hr = hb[s % 3] + (((size_t)(b0 + prow)) << 7);
            unsigned long long vals[4];
            unsigned vm = 0;
#pragma unroll
            for (int j = 0; j < 4; ++j) vals[j] = llc_load64(hr + q + 32 * j);
            int rounds = 0;
            while (true) {
#pragma unroll
                for (int j = 0; j < 4; ++j) {
                    if (!(vm & (1u << j))) {
                        unsigned lo = (unsigned)vals[j];
                        unsigned hi = (unsigned)(vals[j] >> 32);
                        if (lo != 0xFFFFFFFFu && hi != 0xFFFFFFFFu) vm |= 1u << j;
                    }
                }
                if (vm == 0xFu || rounds > (1 << 20)) break;
                __builtin_amdgcn_s_sleep(1);
                ++rounds;
#pragma unroll
                for (int j = 0; j < 4; ++j)
                    if (!(vm & (1u << j))) vals[j] = llc_load64(hr + q + 32 * j);
            }
#pragma unroll
            for (int j = 0; j < 4; ++j)
                *(unsigned long long*)(inb + prow * ROWB + 64 + (q + 32 * j) * 8) = vals[j];
        }

        // sentinel-reset own produced slots in ring buf (s+2)%3 (safe post-poll)
        if (s >= 1 && tid < 128) {
            unsigned long long* rb = hb[(s + 2) % 3]
                + (((size_t)(b0 + (tid >> 3))) << 7) + ut * 8 + (tid & 7);
            llc_store64(rb, ~0ULL);
        }
        // prefetch next xa
        if (s < TSTEPS - 1 && q < 16)
            xa_next = xa32[((size_t)(TSTEPS - 2 - s) * BATCH + b0 + prow) * 16 + q];

        __syncthreads();

        // ---- MFMA: A (16 rows) from LDS, B from regs; bias in acc init ----
        f32x4 acc = { bias, bias, bias, bias };
        const uint8_t* ab = inb + c * ROWB + kq * 16;
#pragma unroll
        for (int kk = 0; kk < KK_N; ++kk) {
            bf16x8 af = *(const bf16x8*)(ab + kk * 64);
            acc = __builtin_amdgcn_mfma_f32_16x16x32_bf16(af, wb[kk], acc, 0, 0, 0);
        }

        // ---- in-wave gate transpose via per-wave scratch (no barrier) ----
        *(f32x4*)(scr + l * 4) = acc;
        float gi = scr[(((rs >> 2) * 16 +  0 + du) << 2) + (rs & 3)];
        float gf = scr[(((rs >> 2) * 16 +  4 + du) << 2) + (rs & 3)];
        float gg = scr[(((rs >> 2) * 16 +  8 + du) << 2) + (rs & 3)];
        float go = scr[(((rs >> 2) * 16 + 12 + du) << 2) + (rs & 3)];

        float i_ = 1.0f / (1.0f + __expf(-gi));
        float f_ = 1.0f / (1.0f + __expf(-gf));
        float o_ = 1.0f / (1.0f + __expf(-go));
        float g_ = 1.0f - 2.0f / (__expf(2.0f * gg) + 1.0f);
        c_reg = f_ * c_reg + i_ * g_;
        float h_ = o_ * (1.0f - 2.0f / (__expf(2.0f * c_reg) + 1.0f));

        const int grow_b = b0 + rs;                    // global batch row
        if (s < TSTEPS - 1) {
            // pack this wave's 4 units -> u64, store by du==0 lane of each row
            unsigned v = (unsigned)f2bf(h_);
            unsigned t1 = (unsigned)__shfl_xor((int)v, 1);
            unsigned packed = v | (t1 << 16);
            unsigned hi = (unsigned)__shfl_xor((int)packed, 2);
            if (du == 0) {
                unsigned long long u64v = (unsigned long long)packed |
                                          ((unsigned long long)hi << 32);
                llc_store64(hb[(s + 1) % 3] + (size_t)grow_b * 128 + ut * 8 + w, u64v);
            }
        } else {
            hfinal[(size_t)grow_b * HID + ug0 + w * 4 + du] = h_;
        }
    }
}

// ---------------------------------------------------------------------------
// heads: mu = exp(h@lin_w.T + lin_b)/10 ; log_var = h@lv_w.T + lv_b - 5
__global__ __launch_bounds__(128) void head_kernel(
    const float* __restrict__ h,
    const float* __restrict__ lin_w, const float* __restrict__ lin_b,
    const float* __restrict__ lv_w,  const float* __restrict__ lv_b,
    float* __restrict__ out)
{
    __shared__ float hl[HID];
    const int b = blockIdx.x, tid = threadIdx.x;
    for (int k = tid; k < HID; k += 128) hl[k] = h[b * HID + k];
    __syncthreads();

    const float* W = (tid < 64) ? lin_w : lv_w;
    const int j = tid & 63;
    const float4* W4 = (const float4*)(W + j * HID);
    float acc = 0.0f;
    for (int k4 = 0; k4 < HID / 4; ++k4) {
        float4 wv = W4[k4];
        float4 hv = *(const float4*)(hl + k4 * 4);
        acc += wv.x * hv.x + wv.y * hv.y + wv.z * hv.z + wv.w * hv.w;
    }

    if (tid < 64) {
        out[b * OUTD + j] = __expf(acc + lin_b[j]) * 0.1f;
    } else {
        out[BATCH * OUTD + b * OUTD + j] = acc + lv_b[j] - 5.0f;
    }
}

// ---------------------------------------------------------------------------
extern "C" void kernel_launch(void* const* d_in, const int* in_sizes, int n_in,
                              void* d_out, int out_size, void* d_ws, size_t ws_size,
                              hipStream_t stream)
{
    const float* x     = (const float*)d_in[0];
    const float* a     = (const float*)d_in[1];
    const float* mask  = (const float*)d_in[2];
    const float* W_ih  = (const float*)d_in[3];
    const float* W_hh  = (const float*)d_in[4];
    const float* b_ih  = (const float*)d_in[5];
    const float* b_hh  = (const float*)d_in[6];
    const float* lin_w = (const float*)d_in[7];
    const float* lin_b = (const float*)d_in[8];
    const float* lv_w  = (const float*)d_in[9];
    const float* lv_b  = (const float*)d_in[10];

    uint8_t* ws = (uint8_t*)d_ws;

    precompute_kernel<<<512, 256, 0, stream>>>(x, a, mask, ws);
    lstm_persist_kernel<<<NBT * NUT, 512, 0, stream>>>(W_ih, W_hh, b_ih, b_hh, ws);
    head_kernel<<<BATCH, 128, 0, stream>>>((const float*)(ws + HF_OFF),
                                           lin_w, lin_b, lv_w, lv_b, (float*)d_out);
}